// Round 1
// baseline (1944.036 us; speedup 1.0000x reference)
//
#include <hip/hip_runtime.h>
#include <math.h>

// Dims: B=64, N=1024, M=32, T=25, R=512, SO=512, OD=10
#define TRW 57            // trace ring width = M + T
#define TRN (TRW * 64)    // 3648 floats per n: trace layout [n][col][b]

__device__ __forceinline__ float wave_sum(float v) {
  #pragma unroll
  for (int off = 32; off; off >>= 1) v += __shfl_xor(v, off, 64);
  return v;
}

template<int NT>
__device__ __forceinline__ float2 block_sum2(float a, float b, float2* sh) {
  constexpr int NW = NT / 64;
  a = wave_sum(a); b = wave_sum(b);
  int w = threadIdx.x >> 6, l = threadIdx.x & 63;
  if (l == 0) sh[w] = make_float2(a, b);
  __syncthreads();
  float2 r = make_float2(0.f, 0.f);
  #pragma unroll
  for (int i = 0; i < NW; i++) { r.x += sh[i].x; r.y += sh[i].y; }
  __syncthreads();
  return r;
}

__device__ __forceinline__ float sigmoidf(float x) {
  return 1.f / (1.f + expf(-x));
}

// ---------------- one-time fused encoder: one block per b ----------------
__global__ __launch_bounds__(512) void k_enc(const float* __restrict__ x,
    const float* __restrict__ w1, const float* __restrict__ b1,
    const float* __restrict__ g1, const float* __restrict__ bn1,
    const float* __restrict__ w2, const float* __restrict__ b2,
    const float* __restrict__ g2, const float* __restrict__ bn2,
    const float* __restrict__ w3, const float* __restrict__ b3,
    const float* __restrict__ kvw, const float* __restrict__ kvb,
    const float* __restrict__ kvg, const float* __restrict__ kvbn,
    const float* __restrict__ ipw, const float* __restrict__ ipb,
    const float* __restrict__ opw, const float* __restrict__ opb,
    float* __restrict__ attn) {
  int b = blockIdx.x, tid = threadIdx.x, w = tid >> 6, l = tid & 63;
  __shared__ float xs[784];
  __shared__ float A[512];
  __shared__ float Bv[512];
  __shared__ float buf1[128];
  __shared__ float buf2[64];
  __shared__ float2 sh[8];
  for (int i = tid; i < 784; i += 512) xs[i] = x[b * 784 + i];
  __syncthreads();
  // L1: 128 outs, K=784
  for (int r = 0; r < 16; r++) {
    int o = r * 8 + w;
    float s = 0.f;
    for (int k = l; k < 784; k += 64) s += xs[k] * w1[o * 784 + k];
    s = wave_sum(s);
    if (l == 0) buf1[o] = s + b1[o];
  }
  __syncthreads();
  {
    float v = (tid < 128) ? buf1[tid] : 0.f;
    float2 s2 = block_sum2<512>(v, v * v, sh);
    if (tid < 128) {
      float mu = s2.x * (1.f / 128.f), var = s2.y * (1.f / 128.f) - mu * mu;
      buf1[tid] = fmaxf((v - mu) * rsqrtf(var + 1e-5f) * g1[tid] + bn1[tid], 0.f);
    }
  }
  __syncthreads();
  // L2: 64 outs, K=128
  for (int r = 0; r < 8; r++) {
    int o = r * 8 + w;
    float s = buf1[l] * w2[o * 128 + l] + buf1[l + 64] * w2[o * 128 + l + 64];
    s = wave_sum(s);
    if (l == 0) buf2[o] = s + b2[o];
  }
  __syncthreads();
  if (tid < 64) {
    float v = buf2[tid];
    float sa = wave_sum(v), sb = wave_sum(v * v);
    float mu = sa * (1.f / 64.f), var = sb * (1.f / 64.f) - mu * mu;
    buf2[tid] = fmaxf((v - mu) * rsqrtf(var + 1e-5f) * g2[tid] + bn2[tid], 0.f);
  }
  __syncthreads();
  // L3: enc (512 outs, K=64)
  for (int r = 0; r < 64; r++) {
    int o = r * 8 + w;
    float s = wave_sum(buf2[l] * w3[o * 64 + l]);
    if (l == 0) A[o] = s + b3[o];
  }
  __syncthreads();
  // kv (512 outs, K=512) + LN
  for (int r = 0; r < 64; r++) {
    int o = r * 8 + w;
    float s = 0.f;
    #pragma unroll
    for (int k = 0; k < 8; k++) s += A[l + 64 * k] * kvw[o * 512 + l + 64 * k];
    s = wave_sum(s);
    if (l == 0) Bv[o] = s + kvb[o];
  }
  __syncthreads();
  {
    float v = Bv[tid];
    float2 s2 = block_sum2<512>(v, v * v, sh);
    float mu = s2.x * (1.f / 512.f), var = s2.y * (1.f / 512.f) - mu * mu;
    Bv[tid] = (v - mu) * rsqrtf(var + 1e-5f) * kvg[tid] + kvbn[tid];
  }
  __syncthreads();
  // v = kv @ Wv^T (in_proj rows [1024:1536))
  for (int r = 0; r < 64; r++) {
    int o = r * 8 + w;
    float s = 0.f;
    #pragma unroll
    for (int k = 0; k < 8; k++) s += Bv[l + 64 * k] * ipw[(1024 + o) * 512 + l + 64 * k];
    s = wave_sum(s);
    if (l == 0) A[o] = s + ipb[1024 + o];
  }
  __syncthreads();
  // attn_out = v @ out_proj^T
  for (int r = 0; r < 64; r++) {
    int o = r * 8 + w;
    float s = 0.f;
    #pragma unroll
    for (int k = 0; k < 8; k++) s += A[l + 64 * k] * opw[o * 512 + l + 64 * k];
    s = wave_sum(s);
    if (l == 0) attn[b * 512 + o] = s + opb[o];
  }
}

// ---------------- one-time setup: trace/state init + weight transposes ----------------
__global__ void k_setup(const float* __restrict__ st, const float* __restrict__ sas,
                        const int* __restrict__ il, const int* __restrict__ ir,
                        const float* __restrict__ opw1, const float* __restrict__ opw2,
                        float* __restrict__ trace, float* __restrict__ act,
                        float* __restrict__ aO, float* __restrict__ bO,
                        float* __restrict__ w1t, float* __restrict__ w2t) {
  long i = (long)blockIdx.x * 256 + threadIdx.x;
  if (i < 2097152) {  // trace init: [n][j][b] = st[n][j]
    int b = (int)(i & 63), j = (int)((i >> 6) & 31), n = (int)(i >> 11);
    trace[n * TRN + j * 64 + b] = st[n * 32 + j];
    return;
  }
  i -= 2097152;
  if (i < 65536) {  // act[b][n] = sas[n]
    act[i] = sas[i & 1023];
    return;
  }
  i -= 65536;
  if (i < 32768) {  // aO/bO
    int o = (int)(i & 511);
    aO[i] = sas[il[o]] * sas[ir[o]];
    bO[i] = 1.f;
    return;
  }
  i -= 32768;
  if (i < 131072) {  // w1t[k*256+o] = opw1[o*512+k]
    int o = (int)(i & 255), k = (int)(i >> 8);
    w1t[i] = opw1[o * 512 + k];
    return;
  }
  i -= 131072;
  if (i < 16384) {  // w2t[k*64+o] = opw2[o*256+k]
    int o = (int)(i & 63), k = (int)(i >> 6);
    w2t[i] = opw2[o * 256 + k];
  }
}

// ---------------- op head (device body, 256 threads/block) ----------------
__device__ void op_body(int b, int t, const float* __restrict__ act,
                        const float* __restrict__ decay,
                        const int* __restrict__ il, const int* __restrict__ ir,
                        float* __restrict__ aO, float* __restrict__ bO,
                        const float* __restrict__ w1t, const float* __restrict__ bb1,
                        const float* __restrict__ g1, const float* __restrict__ bn1,
                        const float* __restrict__ w2t, const float* __restrict__ bb2,
                        const float* __restrict__ g2, const float* __restrict__ bn2,
                        const float* __restrict__ w3, const float* __restrict__ bb3,
                        float* __restrict__ out,
                        float* so, float* p1s, float* qred, float* p2s,
                        float* preds, float2* sh) {
  int tid = threadIdx.x;
  #pragma unroll
  for (int r = 0; r < 2; r++) {
    int o = r * 256 + tid;
    float rr = expf(-fminf(fmaxf(decay[o], 0.f), 15.f));
    float pp = act[b * 1024 + il[o]] * act[b * 1024 + ir[o]];
    float a = rr * aO[b * 512 + o] + pp;
    float bbv = rr * bO[b * 512 + o] + 1.f;
    aO[b * 512 + o] = a;
    bO[b * 512 + o] = bbv;
    so[o] = a * rsqrtf(bbv + 1e-8f);
  }
  __syncthreads();
  // GEMV1: 256 outs, K=512, coalesced k-major weights
  float p = bb1[tid];
  #pragma unroll 8
  for (int k = 0; k < 512; k++) p += so[k] * w1t[k * 256 + tid];
  float2 s = block_sum2<256>(p, p * p, sh);
  {
    float mu = s.x * (1.f / 256.f), var = s.y * (1.f / 256.f) - mu * mu;
    p1s[tid] = fmaxf((p - mu) * rsqrtf(var + 1e-5f) * g1[tid] + bn1[tid], 0.f);
  }
  __syncthreads();
  // GEMV2: 64 outs, K=256 split over 4 groups, coalesced
  {
    int o = tid & 63, tg = tid >> 6;
    float q = 0.f;
    #pragma unroll 4
    for (int j = 0; j < 64; j++) {
      int k = tg * 64 + j;
      q += p1s[k] * w2t[k * 64 + o];
    }
    qred[tid] = q;
  }
  __syncthreads();
  if (tid < 64) {
    float p2 = qred[tid] + qred[tid + 64] + qred[tid + 128] + qred[tid + 192] + bb2[tid];
    float sa = wave_sum(p2), sb = wave_sum(p2 * p2);
    float mu = sa * (1.f / 64.f), var = sb * (1.f / 64.f) - mu * mu;
    float y = (p2 - mu) * rsqrtf(var + 1e-5f) * g2[tid] + bn2[tid];
    p2s[tid] = fmaxf(y, 0.f);
  }
  __syncthreads();
  if (tid < 160) {
    int o = tid >> 4, j = tid & 15;
    const float* w3r = w3 + o * 64 + j * 4;
    const float* pp2 = p2s + j * 4;
    float sv = w3r[0] * pp2[0] + w3r[1] * pp2[1] + w3r[2] * pp2[2] + w3r[3] * pp2[3];
    #pragma unroll
    for (int off = 8; off; off >>= 1) sv += __shfl_xor(sv, off, 64);
    if (j == 0) {
      float pr = sv + bb3[o];
      preds[o] = pr;
      out[b * 250 + o * 25 + t] = pr;
    }
  }
  __syncthreads();
  if (tid == 0) {
    float mx = preds[0];
    #pragma unroll
    for (int k = 1; k < 10; k++) mx = fmaxf(mx, preds[k]);
    float sum = 0.f, e[10];
    #pragma unroll
    for (int k = 0; k < 10; k++) { e[k] = expf(preds[k] - mx); sum += e[k]; }
    float ent = 0.f;
    #pragma unroll
    for (int k = 0; k < 10; k++) {
      float pr = e[k] / sum;
      ent -= pr * logf(pr + 1e-10f);
    }
    ent *= (1.f / 2.302585093f);
    out[16000 + b * 50 + t] = ent;
    out[16000 + b * 50 + 25 + t] = 1.f - ent;
  }
}

// ---------------- fused: syn GEMM (blocks 0..511) + op(t-1) (blocks 512..575) ----
__global__ __launch_bounds__(256) void k_F(const float* __restrict__ attn,
    const float* __restrict__ act, const float* __restrict__ synw,
    float* __restrict__ part,
    const float* __restrict__ decay, const int* __restrict__ il, const int* __restrict__ ir,
    float* __restrict__ aO, float* __restrict__ bO,
    const float* __restrict__ w1t, const float* __restrict__ bb1,
    const float* __restrict__ g1, const float* __restrict__ bn1,
    const float* __restrict__ w2t, const float* __restrict__ bb2,
    const float* __restrict__ g2, const float* __restrict__ bn2,
    const float* __restrict__ w3, const float* __restrict__ bb3,
    float* __restrict__ out, int t) {
  __shared__ __align__(16) float pre_t[32 * 68];
  __shared__ __align__(16) float w_lds[32 * 68];
  __shared__ __align__(16) float so[512];
  __shared__ float p1s[256];
  __shared__ float qred[256];
  __shared__ float p2s[64];
  __shared__ float preds[10];
  __shared__ float2 sh[4];
  int bid = blockIdx.x;
  if (bid >= 512) {
    if (t > 0)
      op_body(bid - 512, t - 1, act, decay, il, ir, aO, bO, w1t, bb1, g1, bn1,
              w2t, bb2, g2, bn2, w3, bb3, out, so, p1s, qred, p2s, preds, sh);
    return;
  }
  int ct = bid & 31;   // column tile (64 cols)
  int kc = bid >> 5;   // 0..15, K-chunk of 96
  int tid = threadIdx.x;
  int tb = tid >> 4, tc = tid & 15;
  int b0 = tb * 4, c0 = tc * 4;
  float acc[4][4];
  #pragma unroll
  for (int i = 0; i < 4; i++)
    #pragma unroll
    for (int j = 0; j < 4; j++) acc[i][j] = 0.f;

  for (int kt = 0; kt < 96; kt += 32) {
    int k0 = kc * 96 + kt;
    #pragma unroll
    for (int r = 0; r < 8; r++) {
      int idx = r * 256 + tid;  // < 2048
      int kk = idx & 31;
      int bb = idx >> 5;
      int kg = k0 + kk;
      float pv = (kg < 512) ? attn[bb * 512 + kg] : act[bb * 1024 + (kg - 512)];
      pre_t[kk * 68 + bb] = pv;
      w_lds[kk * 68 + bb] = synw[(ct * 64 + bb) * 1536 + kg];
    }
    __syncthreads();
    #pragma unroll 8
    for (int kk = 0; kk < 32; kk++) {
      float4 av = *(const float4*)(pre_t + kk * 68 + b0);
      float4 wv = *(const float4*)(w_lds + kk * 68 + c0);
      float a[4] = {av.x, av.y, av.z, av.w};
      float w[4] = {wv.x, wv.y, wv.z, wv.w};
      #pragma unroll
      for (int i = 0; i < 4; i++)
        #pragma unroll
        for (int j = 0; j < 4; j++) acc[i][j] += a[i] * w[j];
    }
    __syncthreads();
  }
  float* pb = part + kc * (64 * 2048);
  #pragma unroll
  for (int i = 0; i < 4; i++) {
    float4 st4 = make_float4(acc[i][0], acc[i][1], acc[i][2], acc[i][3]);
    *(float4*)(pb + (b0 + i) * 2048 + ct * 64 + c0) = st4;
  }
}

__global__ __launch_bounds__(256) void k_op_tail(const float* __restrict__ act,
    const float* __restrict__ decay, const int* __restrict__ il, const int* __restrict__ ir,
    float* __restrict__ aO, float* __restrict__ bO,
    const float* __restrict__ w1t, const float* __restrict__ bb1,
    const float* __restrict__ g1, const float* __restrict__ bn1,
    const float* __restrict__ w2t, const float* __restrict__ bb2,
    const float* __restrict__ g2, const float* __restrict__ bn2,
    const float* __restrict__ w3, const float* __restrict__ bb3,
    float* __restrict__ out) {
  __shared__ __align__(16) float so[512];
  __shared__ float p1s[256];
  __shared__ float qred[256];
  __shared__ float p2s[64];
  __shared__ float preds[10];
  __shared__ float2 sh[4];
  op_body(blockIdx.x, 24, act, decay, il, ir, aO, bO, w1t, bb1, g1, bn1,
          w2t, bb2, g2, bn2, w3, bb3, out, so, p1s, qred, p2s, preds, sh);
}

// sum 16 partials + bias -> GLU -> LN(1024) -> ns[b][n] (coalesced)
__global__ __launch_bounds__(1024) void k_syn_ln(const float* __restrict__ part,
                                                 const float* __restrict__ synb,
                                                 const float* __restrict__ sg,
                                                 const float* __restrict__ sbn,
                                                 float* __restrict__ ns) {
  __shared__ float2 sh[16];
  int b = blockIdx.x, n = threadIdx.x;
  float a = synb[n], g = synb[n + 1024];
  #pragma unroll
  for (int kc = 0; kc < 16; kc++) {
    const float* pb = part + kc * (64 * 2048) + b * 2048;
    a += pb[n];
    g += pb[n + 1024];
  }
  float val = a * sigmoidf(g);
  float2 s = block_sum2<1024>(val, val * val, sh);
  float mu = s.x * (1.f / 1024.f);
  float var = s.y * (1.f / 1024.f) - mu * mu;
  ns[b * 1024 + n] = (val - mu) * rsqrtf(var + 1e-5f) * sg[n] + sbn[n];
}

// per-n NLM; stages window from own trace row + ns column; writes new col to trace
__global__ __launch_bounds__(256) void k_nlm(const float* __restrict__ trace_c,
                                             float* __restrict__ trace,
                                             const float* __restrict__ ns,
                                             const float* __restrict__ w1,
                                             const float* __restrict__ b1,
                                             const float* __restrict__ w2,
                                             const float* __restrict__ b2,
                                             float* __restrict__ act, int t) {
  int n = blockIdx.x;
  int tid = threadIdx.x;
  int tb = tid >> 5;
  int tjj = tid & 31;
  __shared__ __align__(16) float At[32 * 68];  // [m][b]
  __shared__ __align__(16) float w1s[32 * 256];
  __shared__ float b1s[256];
  __shared__ float w2s[128];

  // m = 0..30 from trace cols t+1..t+31 (contiguous 1984 floats)
  const float4* tw4 = (const float4*)(trace_c + n * TRN + (t + 1) * 64);
  #pragma unroll
  for (int r = 0; r < 2; r++) {
    int idx = r * 256 + tid;
    if (idx < 496) {
      float4 f4 = tw4[idx];
      int fo = idx * 4;
      int m = fo >> 6, bb = fo & 63;
      *(float4*)(At + m * 68 + bb) = f4;
    }
  }
  // m = 31 from ns; also persist as trace col 32+t (block owns trace[n])
  if (tid < 64) {
    float v = ns[tid * 1024 + n];
    At[31 * 68 + tid] = v;
    trace[n * TRN + (32 + t) * 64 + tid] = v;
  }
  const float4* w1n = (const float4*)(w1 + n * 8192);
  float4* w1s4 = (float4*)w1s;
  #pragma unroll
  for (int r = 0; r < 8; r++) w1s4[r * 256 + tid] = w1n[r * 256 + tid];
  b1s[tid] = b1[n * 256 + tid];
  if (tid < 128) w2s[tid] = w2[n * 128 + tid];
  __syncthreads();

  float h[8][8];
  #pragma unroll
  for (int jj = 0; jj < 8; jj++) {
    float bv = b1s[tjj + 32 * jj];
    #pragma unroll
    for (int i = 0; i < 8; i++) h[i][jj] = bv;
  }
  for (int m = 0; m < 32; m++) {
    float4 a0 = *(const float4*)(At + m * 68 + tb * 8);
    float4 a1 = *(const float4*)(At + m * 68 + tb * 8 + 4);
    float a[8] = {a0.x, a0.y, a0.z, a0.w, a1.x, a1.y, a1.z, a1.w};
    float w[8];
    #pragma unroll
    for (int jj = 0; jj < 8; jj++) w[jj] = w1s[m * 256 + tjj + 32 * jj];
    #pragma unroll
    for (int i = 0; i < 8; i++)
      #pragma unroll
      for (int jj = 0; jj < 8; jj++) h[i][jj] += a[i] * w[jj];
  }
  float b2n = b2[n];
  #pragma unroll
  for (int i = 0; i < 8; i++) {
    float p = 0.f;
    #pragma unroll
    for (int jj = 0; jj < 4; jj++) {
      float hh = h[i][jj] * sigmoidf(h[i][jj + 4]);
      p += hh * w2s[tjj + 32 * jj];
    }
    #pragma unroll
    for (int off = 16; off > 0; off >>= 1) p += __shfl_xor(p, off, 64);
    if (tjj == 0) act[(tb * 8 + i) * 1024 + n] = p + b2n;
  }
}

extern "C" void kernel_launch(void* const* d_in, const int* in_sizes, int n_in,
                              void* d_out, int out_size, void* d_ws, size_t ws_size,
                              hipStream_t stream) {
  const float* x        = (const float*)d_in[0];
  const float* sas      = (const float*)d_in[1];
  const float* st       = (const float*)d_in[2];
  const float* ie_w1    = (const float*)d_in[3];
  const float* ie_b1    = (const float*)d_in[4];
  const float* ie_g1    = (const float*)d_in[5];
  const float* ie_bn1   = (const float*)d_in[6];
  const float* ie_w2    = (const float*)d_in[7];
  const float* ie_b2    = (const float*)d_in[8];
  const float* ie_g2    = (const float*)d_in[9];
  const float* ie_bn2   = (const float*)d_in[10];
  const float* ie_w3    = (const float*)d_in[11];
  const float* ie_b3    = (const float*)d_in[12];
  const float* kv_w     = (const float*)d_in[13];
  const float* kv_b     = (const float*)d_in[14];
  const float* kv_g     = (const float*)d_in[15];
  const float* kv_bn    = (const float*)d_in[16];
  const float* ip_w     = (const float*)d_in[19];
  const float* ip_b     = (const float*)d_in[20];
  const float* op_w     = (const float*)d_in[21];
  const float* op_b     = (const float*)d_in[22];
  const float* syn_w    = (const float*)d_in[23];
  const float* syn_b    = (const float*)d_in[24];
  const float* syn_g    = (const float*)d_in[25];
  const float* syn_bn   = (const float*)d_in[26];
  const float* nlm_w1   = (const float*)d_in[27];
  const float* nlm_b1   = (const float*)d_in[28];
  const float* nlm_w2   = (const float*)d_in[29];
  const float* nlm_b2   = (const float*)d_in[30];
  const float* decay_o  = (const float*)d_in[32];
  const float* op_w1    = (const float*)d_in[33];
  const float* op_b1    = (const float*)d_in[34];
  const float* op_g1    = (const float*)d_in[35];
  const float* op_bn1   = (const float*)d_in[36];
  const float* op_w2    = (const float*)d_in[37];
  const float* op_b2    = (const float*)d_in[38];
  const float* op_g2    = (const float*)d_in[39];
  const float* op_bn2   = (const float*)d_in[40];
  const float* op_w3    = (const float*)d_in[41];
  const float* op_b3    = (const float*)d_in[42];
  const int* idx_ol     = (const int*)d_in[43];
  const int* idx_or     = (const int*)d_in[44];

  float* out = (float*)d_out;
  float* ws = (float*)d_ws;
  float* attn  = ws;                 // 32768
  float* act   = attn + 32768;       // 65536
  float* aO    = act + 65536;        // 32768
  float* bO    = aO + 32768;         // 32768
  float* ns    = bO + 32768;         // 65536
  float* w1t   = ns + 65536;         // 131072
  float* w2t   = w1t + 131072;       // 16384
  float* part  = w2t + 16384;        // 16*64*2048 = 2097152
  float* trace = part + 2097152;     // 1024*3648 = 3735552  (~25 MB total)

  k_enc<<<64, 512, 0, stream>>>(x, ie_w1, ie_b1, ie_g1, ie_bn1,
                                ie_w2, ie_b2, ie_g2, ie_bn2, ie_w3, ie_b3,
                                kv_w, kv_b, kv_g, kv_bn, ip_w, ip_b, op_w, op_b, attn);
  k_setup<<<9152, 256, 0, stream>>>(st, sas, idx_ol, idx_or, op_w1, op_w2,
                                    trace, act, aO, bO, w1t, w2t);

  for (int t = 0; t < 25; t++) {
    k_F<<<576, 256, 0, stream>>>(attn, act, syn_w, part,
                                 decay_o, idx_ol, idx_or, aO, bO,
                                 w1t, op_b1, op_g1, op_bn1,
                                 w2t, op_b2, op_g2, op_bn2,
                                 op_w3, op_b3, out, t);
    k_syn_ln<<<64, 1024, 0, stream>>>(part, syn_b, syn_g, syn_bn, ns);
    k_nlm<<<1024, 256, 0, stream>>>(trace, trace, ns, nlm_w1, nlm_b1,
                                    nlm_w2, nlm_b2, act, t);
  }
  k_op_tail<<<64, 256, 0, stream>>>(act, decay_o, idx_ol, idx_or, aO, bO,
                                    w1t, op_b1, op_g1, op_bn1,
                                    w2t, op_b2, op_g2, op_bn2,
                                    op_w3, op_b3, out);
}

// Round 2
// 1714.024 us; speedup vs baseline: 1.1342x; 1.1342x over previous
//
#include <hip/hip_runtime.h>
#include <math.h>

// Dims: B=64, N=1024, M=32, T=25, R=512, SO=512, OD=10
#define TRW 57            // trace ring width = M + T
#define TRN (TRW * 64)    // 3648 floats per n: trace layout [n][col][b]

__device__ __forceinline__ float wave_sum(float v) {
  #pragma unroll
  for (int off = 32; off; off >>= 1) v += __shfl_xor(v, off, 64);
  return v;
}

template<int NT>
__device__ __forceinline__ float2 block_sum2(float a, float b, float2* sh) {
  constexpr int NW = NT / 64;
  a = wave_sum(a); b = wave_sum(b);
  int w = threadIdx.x >> 6, l = threadIdx.x & 63;
  if (l == 0) sh[w] = make_float2(a, b);
  __syncthreads();
  float2 r = make_float2(0.f, 0.f);
  #pragma unroll
  for (int i = 0; i < NW; i++) { r.x += sh[i].x; r.y += sh[i].y; }
  __syncthreads();
  return r;
}

__device__ __forceinline__ float sigmoidf(float x) {
  return 1.f / (1.f + expf(-x));
}

// ---------------- one-time fused encoder: one block per b ----------------
// Thread-per-output GEMVs on k-major float4-packed weights (packed in k_setup).
// Layout of packed weights: [kb][o][4] where k = kb*4+kk.
__global__ __launch_bounds__(512) void k_enc(const float* __restrict__ x,
    const float* __restrict__ w1te, const float* __restrict__ b1,
    const float* __restrict__ g1, const float* __restrict__ bn1,
    const float* __restrict__ w2te, const float* __restrict__ b2,
    const float* __restrict__ g2, const float* __restrict__ bn2,
    const float* __restrict__ w3te, const float* __restrict__ b3,
    const float* __restrict__ kvwt, const float* __restrict__ kvb,
    const float* __restrict__ kvg, const float* __restrict__ kvbn,
    const float* __restrict__ vwt, const float* __restrict__ ipb,
    const float* __restrict__ opwt, const float* __restrict__ opb,
    float* __restrict__ attn) {
  int b = blockIdx.x, tid = threadIdx.x;
  __shared__ float xs[784];
  __shared__ float h1[128];
  __shared__ float h2[64];
  __shared__ float enc[512];
  __shared__ float red[512];
  __shared__ float2 sh[8];
  for (int i = tid; i < 784; i += 512) xs[i] = x[b * 784 + i];
  __syncthreads();
  // L1: O=128, K=784 split 4 ways (49 float4-kb each)
  {
    int tg = tid >> 7, o = tid & 127;
    const float4* wp = (const float4*)w1te;
    float s0 = 0.f, s1 = 0.f, s2 = 0.f, s3 = 0.f;
    int kb0 = tg * 49;
    #pragma unroll 7
    for (int j = 0; j < 49; j++) {
      int kb = kb0 + j;
      float4 w4 = wp[kb * 128 + o];
      int k = kb * 4;
      s0 += xs[k] * w4.x; s1 += xs[k + 1] * w4.y;
      s2 += xs[k + 2] * w4.z; s3 += xs[k + 3] * w4.w;
    }
    red[tid] = (s0 + s1) + (s2 + s3);
    __syncthreads();
    float v = 0.f;
    if (tid < 128)
      v = red[tid] + red[tid + 128] + red[tid + 256] + red[tid + 384] + b1[tid];
    float2 s2v = block_sum2<512>(tid < 128 ? v : 0.f, tid < 128 ? v * v : 0.f, sh);
    if (tid < 128) {
      float mu = s2v.x * (1.f / 128.f), var = s2v.y * (1.f / 128.f) - mu * mu;
      h1[tid] = fmaxf((v - mu) * rsqrtf(var + 1e-5f) * g1[tid] + bn1[tid], 0.f);
    }
  }
  __syncthreads();
  // L2: O=64, K=128 (wave 0 only) + LN64
  if (tid < 64) {
    const float4* wp = (const float4*)w2te;
    float s0 = 0.f, s1 = 0.f, s2 = 0.f, s3 = 0.f;
    #pragma unroll 8
    for (int kb = 0; kb < 32; kb++) {
      float4 w4 = wp[kb * 64 + tid];
      int k = kb * 4;
      s0 += h1[k] * w4.x; s1 += h1[k + 1] * w4.y;
      s2 += h1[k + 2] * w4.z; s3 += h1[k + 3] * w4.w;
    }
    float s = (s0 + s1) + (s2 + s3) + b2[tid];
    float sa = wave_sum(s), sb = wave_sum(s * s);
    float mu = sa * (1.f / 64.f), var = sb * (1.f / 64.f) - mu * mu;
    h2[tid] = fmaxf((s - mu) * rsqrtf(var + 1e-5f) * g2[tid] + bn2[tid], 0.f);
  }
  __syncthreads();
  // L3: O=512, K=64
  {
    const float4* wp = (const float4*)w3te;
    float s0 = 0.f, s1 = 0.f, s2 = 0.f, s3 = 0.f;
    #pragma unroll 8
    for (int kb = 0; kb < 16; kb++) {
      float4 w4 = wp[kb * 512 + tid];
      int k = kb * 4;
      s0 += h2[k] * w4.x; s1 += h2[k + 1] * w4.y;
      s2 += h2[k + 2] * w4.z; s3 += h2[k + 3] * w4.w;
    }
    enc[tid] = (s0 + s1) + (s2 + s3) + b3[tid];
  }
  __syncthreads();
  // kv: O=512, K=512 + LN512
  {
    const float4* wp = (const float4*)kvwt;
    float s0 = 0.f, s1 = 0.f, s2 = 0.f, s3 = 0.f;
    #pragma unroll 8
    for (int kb = 0; kb < 128; kb++) {
      float4 w4 = wp[kb * 512 + tid];
      int k = kb * 4;
      s0 += enc[k] * w4.x; s1 += enc[k + 1] * w4.y;
      s2 += enc[k + 2] * w4.z; s3 += enc[k + 3] * w4.w;
    }
    float s = (s0 + s1) + (s2 + s3) + kvb[tid];
    float2 s2v = block_sum2<512>(s, s * s, sh);
    float mu = s2v.x * (1.f / 512.f), var = s2v.y * (1.f / 512.f) - mu * mu;
    red[tid] = (s - mu) * rsqrtf(var + 1e-5f) * kvg[tid] + kvbn[tid];
  }
  __syncthreads();
  // v = kv @ Wv^T: O=512, K=512
  {
    const float4* wp = (const float4*)vwt;
    float s0 = 0.f, s1 = 0.f, s2 = 0.f, s3 = 0.f;
    #pragma unroll 8
    for (int kb = 0; kb < 128; kb++) {
      float4 w4 = wp[kb * 512 + tid];
      int k = kb * 4;
      s0 += red[k] * w4.x; s1 += red[k + 1] * w4.y;
      s2 += red[k + 2] * w4.z; s3 += red[k + 3] * w4.w;
    }
    enc[tid] = (s0 + s1) + (s2 + s3) + ipb[1024 + tid];
  }
  __syncthreads();
  // attn_out = v @ out_proj^T: O=512, K=512
  {
    const float4* wp = (const float4*)opwt;
    float s0 = 0.f, s1 = 0.f, s2 = 0.f, s3 = 0.f;
    #pragma unroll 8
    for (int kb = 0; kb < 128; kb++) {
      float4 w4 = wp[kb * 512 + tid];
      int k = kb * 4;
      s0 += enc[k] * w4.x; s1 += enc[k + 1] * w4.y;
      s2 += enc[k + 2] * w4.z; s3 += enc[k + 3] * w4.w;
    }
    attn[b * 512 + tid] = (s0 + s1) + (s2 + s3) + opb[tid];
  }
}

// ---------------- one-time setup: trace/state init + weight transposes ----------------
__global__ void k_setup(const float* __restrict__ st, const float* __restrict__ sas,
                        const int* __restrict__ il, const int* __restrict__ ir,
                        const float* __restrict__ opw1, const float* __restrict__ opw2,
                        const float* __restrict__ iew1, const float* __restrict__ iew2,
                        const float* __restrict__ iew3, const float* __restrict__ kvw,
                        const float* __restrict__ ipw, const float* __restrict__ opw,
                        float* __restrict__ trace, float* __restrict__ act,
                        float* __restrict__ aO, float* __restrict__ bO,
                        float* __restrict__ w1t, float* __restrict__ w2t,
                        float* __restrict__ w1te, float* __restrict__ w2te,
                        float* __restrict__ w3te, float* __restrict__ kvwt,
                        float* __restrict__ vwt, float* __restrict__ opwt) {
  long i = (long)blockIdx.x * 256 + threadIdx.x;
  if (i < 2097152) {  // trace init: [n][j][b] = st[n][j]
    int b = (int)(i & 63), j = (int)((i >> 6) & 31), n = (int)(i >> 11);
    trace[n * TRN + j * 64 + b] = st[n * 32 + j];
    return;
  }
  i -= 2097152;
  if (i < 65536) {  // act[b][n] = sas[n]
    act[i] = sas[i & 1023];
    return;
  }
  i -= 65536;
  if (i < 32768) {  // aO/bO
    int o = (int)(i & 511);
    aO[i] = sas[il[o]] * sas[ir[o]];
    bO[i] = 1.f;
    return;
  }
  i -= 32768;
  if (i < 131072) {  // w1t[k*256+o] = opw1[o*512+k]
    int o = (int)(i & 255), k = (int)(i >> 8);
    w1t[i] = opw1[o * 512 + k];
    return;
  }
  i -= 131072;
  if (i < 16384) {  // w2t[k*64+o] = opw2[o*256+k]
    int o = (int)(i & 63), k = (int)(i >> 6);
    w2t[i] = opw2[o * 256 + k];
    return;
  }
  i -= 16384;
  // encoder packed transposes: layout [kb][o][4], k = kb*4+kk
  if (i < 100352) {  // w1te: O=128, K=784
    int kk = (int)(i & 3), o = (int)((i >> 2) & 127), kb = (int)(i >> 9);
    w1te[i] = iew1[o * 784 + kb * 4 + kk];
    return;
  }
  i -= 100352;
  if (i < 8192) {  // w2te: O=64, K=128
    int kk = (int)(i & 3), o = (int)((i >> 2) & 63), kb = (int)(i >> 8);
    w2te[i] = iew2[o * 128 + kb * 4 + kk];
    return;
  }
  i -= 8192;
  if (i < 32768) {  // w3te: O=512, K=64
    int kk = (int)(i & 3), o = (int)((i >> 2) & 511), kb = (int)(i >> 11);
    w3te[i] = iew3[o * 64 + kb * 4 + kk];
    return;
  }
  i -= 32768;
  if (i < 262144) {  // kvwt: O=512, K=512
    int kk = (int)(i & 3), o = (int)((i >> 2) & 511), kb = (int)(i >> 11);
    kvwt[i] = kvw[o * 512 + kb * 4 + kk];
    return;
  }
  i -= 262144;
  if (i < 262144) {  // vwt: in_proj rows [1024:1536)
    int kk = (int)(i & 3), o = (int)((i >> 2) & 511), kb = (int)(i >> 11);
    vwt[i] = ipw[(1024 + o) * 512 + kb * 4 + kk];
    return;
  }
  i -= 262144;
  if (i < 262144) {  // opwt
    int kk = (int)(i & 3), o = (int)((i >> 2) & 511), kb = (int)(i >> 11);
    opwt[i] = opw[o * 512 + kb * 4 + kk];
  }
}

// ---------------- op head (device body, 256 threads/block) ----------------
__device__ void op_body(int b, int t, const float* __restrict__ act,
                        const float* __restrict__ decay,
                        const int* __restrict__ il, const int* __restrict__ ir,
                        float* __restrict__ aO, float* __restrict__ bO,
                        const float* __restrict__ w1t, const float* __restrict__ bb1,
                        const float* __restrict__ g1, const float* __restrict__ bn1,
                        const float* __restrict__ w2t, const float* __restrict__ bb2,
                        const float* __restrict__ g2, const float* __restrict__ bn2,
                        const float* __restrict__ w3, const float* __restrict__ bb3,
                        float* __restrict__ out,
                        float* so, float* p1s, float* qred, float* p2s,
                        float* preds, float2* sh) {
  int tid = threadIdx.x;
  #pragma unroll
  for (int r = 0; r < 2; r++) {
    int o = r * 256 + tid;
    float rr = expf(-fminf(fmaxf(decay[o], 0.f), 15.f));
    float pp = act[b * 1024 + il[o]] * act[b * 1024 + ir[o]];
    float a = rr * aO[b * 512 + o] + pp;
    float bbv = rr * bO[b * 512 + o] + 1.f;
    aO[b * 512 + o] = a;
    bO[b * 512 + o] = bbv;
    so[o] = a * rsqrtf(bbv + 1e-8f);
  }
  __syncthreads();
  // GEMV1: 256 outs, K=512, coalesced k-major weights
  float p = bb1[tid];
  #pragma unroll 8
  for (int k = 0; k < 512; k++) p += so[k] * w1t[k * 256 + tid];
  float2 s = block_sum2<256>(p, p * p, sh);
  {
    float mu = s.x * (1.f / 256.f), var = s.y * (1.f / 256.f) - mu * mu;
    p1s[tid] = fmaxf((p - mu) * rsqrtf(var + 1e-5f) * g1[tid] + bn1[tid], 0.f);
  }
  __syncthreads();
  // GEMV2: 64 outs, K=256 split over 4 groups, coalesced
  {
    int o = tid & 63, tg = tid >> 6;
    float q = 0.f;
    #pragma unroll 4
    for (int j = 0; j < 64; j++) {
      int k = tg * 64 + j;
      q += p1s[k] * w2t[k * 64 + o];
    }
    qred[tid] = q;
  }
  __syncthreads();
  if (tid < 64) {
    float p2 = qred[tid] + qred[tid + 64] + qred[tid + 128] + qred[tid + 192] + bb2[tid];
    float sa = wave_sum(p2), sb = wave_sum(p2 * p2);
    float mu = sa * (1.f / 64.f), var = sb * (1.f / 64.f) - mu * mu;
    float y = (p2 - mu) * rsqrtf(var + 1e-5f) * g2[tid] + bn2[tid];
    p2s[tid] = fmaxf(y, 0.f);
  }
  __syncthreads();
  if (tid < 160) {
    int o = tid >> 4, j = tid & 15;
    const float* w3r = w3 + o * 64 + j * 4;
    const float* pp2 = p2s + j * 4;
    float sv = w3r[0] * pp2[0] + w3r[1] * pp2[1] + w3r[2] * pp2[2] + w3r[3] * pp2[3];
    #pragma unroll
    for (int off = 8; off; off >>= 1) sv += __shfl_xor(sv, off, 64);
    if (j == 0) {
      float pr = sv + bb3[o];
      preds[o] = pr;
      out[b * 250 + o * 25 + t] = pr;
    }
  }
  __syncthreads();
  if (tid == 0) {
    float mx = preds[0];
    #pragma unroll
    for (int k = 1; k < 10; k++) mx = fmaxf(mx, preds[k]);
    float sum = 0.f, e[10];
    #pragma unroll
    for (int k = 0; k < 10; k++) { e[k] = expf(preds[k] - mx); sum += e[k]; }
    float ent = 0.f;
    #pragma unroll
    for (int k = 0; k < 10; k++) {
      float pr = e[k] / sum;
      ent -= pr * logf(pr + 1e-10f);
    }
    ent *= (1.f / 2.302585093f);
    out[16000 + b * 50 + t] = ent;
    out[16000 + b * 50 + 25 + t] = 1.f - ent;
  }
}

// ---------------- fused: syn GEMM (blocks 0..511) + op(t-1) (blocks 512..575) ----
__global__ __launch_bounds__(256) void k_F(const float* __restrict__ attn,
    const float* __restrict__ act, const float* __restrict__ synw,
    float* __restrict__ part,
    const float* __restrict__ decay, const int* __restrict__ il, const int* __restrict__ ir,
    float* __restrict__ aO, float* __restrict__ bO,
    const float* __restrict__ w1t, const float* __restrict__ bb1,
    const float* __restrict__ g1, const float* __restrict__ bn1,
    const float* __restrict__ w2t, const float* __restrict__ bb2,
    const float* __restrict__ g2, const float* __restrict__ bn2,
    const float* __restrict__ w3, const float* __restrict__ bb3,
    float* __restrict__ out, int t) {
  __shared__ __align__(16) float pre_t[32 * 68];
  __shared__ __align__(16) float w_lds[32 * 68];
  __shared__ __align__(16) float so[512];
  __shared__ float p1s[256];
  __shared__ float qred[256];
  __shared__ float p2s[64];
  __shared__ float preds[10];
  __shared__ float2 sh[4];
  int bid = blockIdx.x;
  if (bid >= 512) {
    if (t > 0)
      op_body(bid - 512, t - 1, act, decay, il, ir, aO, bO, w1t, bb1, g1, bn1,
              w2t, bb2, g2, bn2, w3, bb3, out, so, p1s, qred, p2s, preds, sh);
    return;
  }
  int ct = bid & 31;   // column tile (64 cols)
  int kc = bid >> 5;   // 0..15, K-chunk of 96
  int tid = threadIdx.x;
  int tb = tid >> 4, tc = tid & 15;
  int b0 = tb * 4, c0 = tc * 4;
  float acc[4][4];
  #pragma unroll
  for (int i = 0; i < 4; i++)
    #pragma unroll
    for (int j = 0; j < 4; j++) acc[i][j] = 0.f;

  for (int kt = 0; kt < 96; kt += 32) {
    int k0 = kc * 96 + kt;
    #pragma unroll
    for (int r = 0; r < 8; r++) {
      int idx = r * 256 + tid;  // < 2048
      int kk = idx & 31;
      int bb = idx >> 5;
      int kg = k0 + kk;
      float pv = (kg < 512) ? attn[bb * 512 + kg] : act[bb * 1024 + (kg - 512)];
      pre_t[kk * 68 + bb] = pv;
      w_lds[kk * 68 + bb] = synw[(ct * 64 + bb) * 1536 + kg];
    }
    __syncthreads();
    #pragma unroll 8
    for (int kk = 0; kk < 32; kk++) {
      float4 av = *(const float4*)(pre_t + kk * 68 + b0);
      float4 wv = *(const float4*)(w_lds + kk * 68 + c0);
      float a[4] = {av.x, av.y, av.z, av.w};
      float w[4] = {wv.x, wv.y, wv.z, wv.w};
      #pragma unroll
      for (int i = 0; i < 4; i++)
        #pragma unroll
        for (int j = 0; j < 4; j++) acc[i][j] += a[i] * w[j];
    }
    __syncthreads();
  }
  float* pb = part + kc * (64 * 2048);
  #pragma unroll
  for (int i = 0; i < 4; i++) {
    float4 st4 = make_float4(acc[i][0], acc[i][1], acc[i][2], acc[i][3]);
    *(float4*)(pb + (b0 + i) * 2048 + ct * 64 + c0) = st4;
  }
}

__global__ __launch_bounds__(256) void k_op_tail(const float* __restrict__ act,
    const float* __restrict__ decay, const int* __restrict__ il, const int* __restrict__ ir,
    float* __restrict__ aO, float* __restrict__ bO,
    const float* __restrict__ w1t, const float* __restrict__ bb1,
    const float* __restrict__ g1, const float* __restrict__ bn1,
    const float* __restrict__ w2t, const float* __restrict__ bb2,
    const float* __restrict__ g2, const float* __restrict__ bn2,
    const float* __restrict__ w3, const float* __restrict__ bb3,
    float* __restrict__ out) {
  __shared__ __align__(16) float so[512];
  __shared__ float p1s[256];
  __shared__ float qred[256];
  __shared__ float p2s[64];
  __shared__ float preds[10];
  __shared__ float2 sh[4];
  op_body(blockIdx.x, 24, act, decay, il, ir, aO, bO, w1t, bb1, g1, bn1,
          w2t, bb2, g2, bn2, w3, bb3, out, so, p1s, qred, p2s, preds, sh);
}

// sum 16 partials + bias -> GLU -> LN(1024) -> ns[b][n] (coalesced)
__global__ __launch_bounds__(1024) void k_syn_ln(const float* __restrict__ part,
                                                 const float* __restrict__ synb,
                                                 const float* __restrict__ sg,
                                                 const float* __restrict__ sbn,
                                                 float* __restrict__ ns) {
  __shared__ float2 sh[16];
  int b = blockIdx.x, n = threadIdx.x;
  float a = synb[n], g = synb[n + 1024];
  #pragma unroll
  for (int kc = 0; kc < 16; kc++) {
    const float* pb = part + kc * (64 * 2048) + b * 2048;
    a += pb[n];
    g += pb[n + 1024];
  }
  float val = a * sigmoidf(g);
  float2 s = block_sum2<1024>(val, val * val, sh);
  float mu = s.x * (1.f / 1024.f);
  float var = s.y * (1.f / 1024.f) - mu * mu;
  ns[b * 1024 + n] = (val - mu) * rsqrtf(var + 1e-5f) * sg[n] + sbn[n];
}

// per-n NLM; stages window from own trace row + ns column; writes new col to trace
__global__ __launch_bounds__(256) void k_nlm(const float* __restrict__ trace_c,
                                             float* __restrict__ trace,
                                             const float* __restrict__ ns,
                                             const float* __restrict__ w1,
                                             const float* __restrict__ b1,
                                             const float* __restrict__ w2,
                                             const float* __restrict__ b2,
                                             float* __restrict__ act, int t) {
  int n = blockIdx.x;
  int tid = threadIdx.x;
  int tb = tid >> 5;
  int tjj = tid & 31;
  __shared__ __align__(16) float At[32 * 68];  // [m][b]
  __shared__ __align__(16) float w1s[32 * 256];
  __shared__ float b1s[256];
  __shared__ float w2s[128];

  // m = 0..30 from trace cols t+1..t+31 (contiguous 1984 floats)
  const float4* tw4 = (const float4*)(trace_c + n * TRN + (t + 1) * 64);
  #pragma unroll
  for (int r = 0; r < 2; r++) {
    int idx = r * 256 + tid;
    if (idx < 496) {
      float4 f4 = tw4[idx];
      int fo = idx * 4;
      int m = fo >> 6, bb = fo & 63;
      *(float4*)(At + m * 68 + bb) = f4;
    }
  }
  // m = 31 from ns; also persist as trace col 32+t (block owns trace[n])
  if (tid < 64) {
    float v = ns[tid * 1024 + n];
    At[31 * 68 + tid] = v;
    trace[n * TRN + (32 + t) * 64 + tid] = v;
  }
  const float4* w1n = (const float4*)(w1 + n * 8192);
  float4* w1s4 = (float4*)w1s;
  #pragma unroll
  for (int r = 0; r < 8; r++) w1s4[r * 256 + tid] = w1n[r * 256 + tid];
  b1s[tid] = b1[n * 256 + tid];
  if (tid < 128) w2s[tid] = w2[n * 128 + tid];
  __syncthreads();

  float h[8][8];
  #pragma unroll
  for (int jj = 0; jj < 8; jj++) {
    float bv = b1s[tjj + 32 * jj];
    #pragma unroll
    for (int i = 0; i < 8; i++) h[i][jj] = bv;
  }
  for (int m = 0; m < 32; m++) {
    float4 a0 = *(const float4*)(At + m * 68 + tb * 8);
    float4 a1 = *(const float4*)(At + m * 68 + tb * 8 + 4);
    float a[8] = {a0.x, a0.y, a0.z, a0.w, a1.x, a1.y, a1.z, a1.w};
    float w[8];
    #pragma unroll
    for (int jj = 0; jj < 8; jj++) w[jj] = w1s[m * 256 + tjj + 32 * jj];
    #pragma unroll
    for (int i = 0; i < 8; i++)
      #pragma unroll
      for (int jj = 0; jj < 8; jj++) h[i][jj] += a[i] * w[jj];
  }
  float b2n = b2[n];
  #pragma unroll
  for (int i = 0; i < 8; i++) {
    float p = 0.f;
    #pragma unroll
    for (int jj = 0; jj < 4; jj++) {
      float hh = h[i][jj] * sigmoidf(h[i][jj + 4]);
      p += hh * w2s[tjj + 32 * jj];
    }
    #pragma unroll
    for (int off = 16; off > 0; off >>= 1) p += __shfl_xor(p, off, 64);
    if (tjj == 0) act[(tb * 8 + i) * 1024 + n] = p + b2n;
  }
}

extern "C" void kernel_launch(void* const* d_in, const int* in_sizes, int n_in,
                              void* d_out, int out_size, void* d_ws, size_t ws_size,
                              hipStream_t stream) {
  const float* x        = (const float*)d_in[0];
  const float* sas      = (const float*)d_in[1];
  const float* st       = (const float*)d_in[2];
  const float* ie_w1    = (const float*)d_in[3];
  const float* ie_b1    = (const float*)d_in[4];
  const float* ie_g1    = (const float*)d_in[5];
  const float* ie_bn1   = (const float*)d_in[6];
  const float* ie_w2    = (const float*)d_in[7];
  const float* ie_b2    = (const float*)d_in[8];
  const float* ie_g2    = (const float*)d_in[9];
  const float* ie_bn2   = (const float*)d_in[10];
  const float* ie_w3    = (const float*)d_in[11];
  const float* ie_b3    = (const float*)d_in[12];
  const float* kv_w     = (const float*)d_in[13];
  const float* kv_b     = (const float*)d_in[14];
  const float* kv_g     = (const float*)d_in[15];
  const float* kv_bn    = (const float*)d_in[16];
  const float* ip_w     = (const float*)d_in[19];
  const float* ip_b     = (const float*)d_in[20];
  const float* op_w     = (const float*)d_in[21];
  const float* op_b     = (const float*)d_in[22];
  const float* syn_w    = (const float*)d_in[23];
  const float* syn_b    = (const float*)d_in[24];
  const float* syn_g    = (const float*)d_in[25];
  const float* syn_bn   = (const float*)d_in[26];
  const float* nlm_w1   = (const float*)d_in[27];
  const float* nlm_b1   = (const float*)d_in[28];
  const float* nlm_w2   = (const float*)d_in[29];
  const float* nlm_b2   = (const float*)d_in[30];
  const float* decay_o  = (const float*)d_in[32];
  const float* op_w1    = (const float*)d_in[33];
  const float* op_b1    = (const float*)d_in[34];
  const float* op_g1    = (const float*)d_in[35];
  const float* op_bn1   = (const float*)d_in[36];
  const float* op_w2    = (const float*)d_in[37];
  const float* op_b2    = (const float*)d_in[38];
  const float* op_g2    = (const float*)d_in[39];
  const float* op_bn2   = (const float*)d_in[40];
  const float* op_w3    = (const float*)d_in[41];
  const float* op_b3    = (const float*)d_in[42];
  const int* idx_ol     = (const int*)d_in[43];
  const int* idx_or     = (const int*)d_in[44];

  float* out = (float*)d_out;
  float* ws = (float*)d_ws;
  float* attn  = ws;                 // 32768
  float* act   = attn + 32768;       // 65536
  float* aO    = act + 65536;        // 32768
  float* bO    = aO + 32768;         // 32768
  float* ns    = bO + 32768;         // 65536
  float* w1t   = ns + 65536;         // 131072
  float* w2t   = w1t + 131072;       // 16384
  float* part  = w2t + 16384;        // 16*64*2048 = 2097152
  float* trace = part + 2097152;     // 1024*3648 = 3735552  (~25 MB total)

  // packed encoder weights live inside `part` (free until k_F t=0, which
  // runs after k_enc in stream order)
  float* w1te = part;                // 100352
  float* w2te = w1te + 100352;       // 8192
  float* w3te = w2te + 8192;         // 32768
  float* kvwt = w3te + 32768;        // 262144
  float* vwt  = kvwt + 262144;       // 262144
  float* opwt = vwt + 262144;        // 262144  (total 927744 < 2097152)

  k_setup<<<12776, 256, 0, stream>>>(st, sas, idx_ol, idx_or, op_w1, op_w2,
                                     ie_w1, ie_w2, ie_w3, kv_w, ip_w, op_w,
                                     trace, act, aO, bO, w1t, w2t,
                                     w1te, w2te, w3te, kvwt, vwt, opwt);
  k_enc<<<64, 512, 0, stream>>>(x, w1te, ie_b1, ie_g1, ie_bn1,
                                w2te, ie_b2, ie_g2, ie_bn2, w3te, ie_b3,
                                kvwt, kv_b, kv_g, kv_bn, vwt, ip_b,
                                opwt, op_b, attn);

  for (int t = 0; t < 25; t++) {
    k_F<<<576, 256, 0, stream>>>(attn, act, syn_w, part,
                                 decay_o, idx_ol, idx_or, aO, bO,
                                 w1t, op_b1, op_g1, op_bn1,
                                 w2t, op_b2, op_g2, op_bn2,
                                 op_w3, op_b3, out, t);
    k_syn_ln<<<64, 1024, 0, stream>>>(part, syn_b, syn_g, syn_bn, ns);
    k_nlm<<<1024, 256, 0, stream>>>(trace, trace, ns, nlm_w1, nlm_b1,
                                    nlm_w2, nlm_b2, act, t);
  }
  k_op_tail<<<64, 256, 0, stream>>>(act, decay_o, idx_ol, idx_or, aO, bO,
                                    w1t, op_b1, op_g1, op_bn1,
                                    w2t, op_b2, op_g2, op_bn2,
                                    op_w3, op_b3, out);
}